// Round 1
// baseline (67.559 us; speedup 1.0000x reference)
//
#include <hip/hip_runtime.h>
#include <float.h>
#include <math.h>

// Problem constants (from reference): B=32, L=128, D=16, M=4
#define B_ 32
#define L_ 128
#define D_ 16
#define M_ 4
#define EPS_ 0.001f

// One block per (b,d) series. 256 threads = 4 waves.
// Phase 1: load L=128 samples, min/max reduce, normalize -> xn, s=sqrt(1-xn^2) in LDS.
// Phase 2: argmax over 4 weights (block-uniform), emit 128x128 image as float4 stores.
// Trig identities remove arccos/cos/sin entirely:
//   gasf = cos(pi+pj) = xn_i*xn_j - s_i*s_j
//   gadf = sin(pi-pj) = s_i*xn_j - xn_i*s_j      (phi in [0,pi] => sin(phi)>=0)
//   rp   = 1 - |xn_i - xn_j|
//   outer= xn_i * xn_j
// scale = 1 - stop_grad(w) + w == 1.0 in forward, so output == selected image.
__global__ __launch_bounds__(256) void mt2v_img_kernel(const float* __restrict__ x,
                                                       const float* __restrict__ w,
                                                       float* __restrict__ out) {
    const int bd = blockIdx.x;      // b*D + d, 0..511
    const int b  = bd >> 4;         // / D_ (D_=16)
    const int d  = bd & (D_ - 1);
    const int t  = threadIdx.x;

    __shared__ float xn[L_];
    __shared__ float sq[L_];
    __shared__ float wred[8];       // 4 waves x {min,max}

    // ---- load series (x is [B, L, D], stride D between samples) ----
    float v = 0.0f;
    if (t < L_) v = x[(b * L_ + t) * D_ + d];

    // ---- min/max reduction: shuffle within wave, LDS across waves ----
    float mn = (t < L_) ? v : FLT_MAX;
    float mx = (t < L_) ? v : -FLT_MAX;
    #pragma unroll
    for (int off = 32; off > 0; off >>= 1) {
        mn = fminf(mn, __shfl_down(mn, off, 64));
        mx = fmaxf(mx, __shfl_down(mx, off, 64));
    }
    const int wave = t >> 6;
    if ((t & 63) == 0) { wred[wave * 2] = mn; wred[wave * 2 + 1] = mx; }
    __syncthreads();
    mn = fminf(wred[0], wred[2]);   // only waves 0,1 hold real data (t<128)
    mx = fmaxf(wred[1], wred[3]);

    // ---- normalize, clip, precompute sqrt(1-xn^2) ----
    if (t < L_) {
        float r  = 2.0f / (mx - mn + 1e-8f);
        float xv = (v - mn) * r - 1.0f;
        xv = fminf(fmaxf(xv, -1.0f + EPS_), 1.0f - EPS_);
        xn[t] = xv;
        sq[t] = sqrtf(1.0f - xv * xv);
    }

    // ---- argmax over M=4 weights (first-max tie-break like jnp.argmax) ----
    const float* wp = w + bd * M_;
    float w0 = wp[0], w1 = wp[1], w2 = wp[2], w3 = wp[3];
    int   m = 0;
    float best = w0;
    if (w1 > best) { best = w1; m = 1; }
    if (w2 > best) { best = w2; m = 2; }
    if (w3 > best) { best = w3; m = 3; }
    __syncthreads();

    // ---- emit image: 4096 float4 stores per block, 16 per thread ----
    float4*       outv = reinterpret_cast<float4*>(out + (size_t)bd * (L_ * L_));
    const float4* xnv  = reinterpret_cast<const float4*>(xn);
    const float4* sqv  = reinterpret_cast<const float4*>(sq);

    if (m == 0) {            // GASF
        #pragma unroll
        for (int it = 0; it < 16; ++it) {
            int q = t + it * 256;
            int i = q >> 5;          // row 0..127
            int c = q & 31;          // float4 col 0..31
            float xi = xn[i], si = sq[i];
            float4 xj = xnv[c], sj = sqv[c];
            float4 r;
            r.x = xi * xj.x - si * sj.x;
            r.y = xi * xj.y - si * sj.y;
            r.z = xi * xj.z - si * sj.z;
            r.w = xi * xj.w - si * sj.w;
            outv[q] = r;
        }
    } else if (m == 1) {     // GADF
        #pragma unroll
        for (int it = 0; it < 16; ++it) {
            int q = t + it * 256;
            int i = q >> 5;
            int c = q & 31;
            float xi = xn[i], si = sq[i];
            float4 xj = xnv[c], sj = sqv[c];
            float4 r;
            r.x = si * xj.x - xi * sj.x;
            r.y = si * xj.y - xi * sj.y;
            r.z = si * xj.z - xi * sj.z;
            r.w = si * xj.w - xi * sj.w;
            outv[q] = r;
        }
    } else if (m == 2) {     // recurrence plot
        #pragma unroll
        for (int it = 0; it < 16; ++it) {
            int q = t + it * 256;
            int i = q >> 5;
            int c = q & 31;
            float xi = xn[i];
            float4 xj = xnv[c];
            float4 r;
            r.x = 1.0f - fabsf(xi - xj.x);
            r.y = 1.0f - fabsf(xi - xj.y);
            r.z = 1.0f - fabsf(xi - xj.z);
            r.w = 1.0f - fabsf(xi - xj.w);
            outv[q] = r;
        }
    } else {                 // outer product
        #pragma unroll
        for (int it = 0; it < 16; ++it) {
            int q = t + it * 256;
            int i = q >> 5;
            int c = q & 31;
            float xi = xn[i];
            float4 xj = xnv[c];
            float4 r;
            r.x = xi * xj.x;
            r.y = xi * xj.y;
            r.z = xi * xj.z;
            r.w = xi * xj.w;
            outv[q] = r;
        }
    }
}

extern "C" void kernel_launch(void* const* d_in, const int* in_sizes, int n_in,
                              void* d_out, int out_size, void* d_ws, size_t ws_size,
                              hipStream_t stream) {
    const float* x  = (const float*)d_in[0];   // [B, L, D] f32
    const float* w  = (const float*)d_in[1];   // [B, D, M] f32
    float*       o  = (float*)d_out;           // [B, D, 1, L, L] f32

    dim3 grid(B_ * D_);   // 512 blocks, one per (b,d)
    dim3 block(256);
    hipLaunchKernelGGL(mt2v_img_kernel, grid, block, 0, stream, x, w, o);
}